// Round 1
// baseline (833.306 us; speedup 1.0000x reference)
//
#include <hip/hip_runtime.h>

#define B_N 4096
#define D_N 1024
#define L_N 16384
#define K_N 64
#define CAP 512
#define CNT_STRIDE 16   // one cand counter per 64B cache line

typedef __attribute__((ext_vector_type(8))) short bf16x8;
typedef __attribute__((ext_vector_type(4))) float f32x4;

__device__ __forceinline__ unsigned short f2bf(float f) {
  union { float f; unsigned int u; } v; v.f = f;
  unsigned int r = v.u + 0x7FFFu + ((v.u >> 16) & 1u);
  return (unsigned short)(r >> 16);
}
__device__ __forceinline__ float bf2f(unsigned short u) {
  union { unsigned int u; float f; } v; v.u = (unsigned int)u << 16;
  return v.f;
}

// ---------------- fused prep: W_enc->bf16 | xbar+sigma+cnt0 | W_dec transpose ----------------
// grid = 16384 (wenc) + 4096 (xbar) + 16384 (transpose) = 36864 blocks
__global__ __launch_bounds__(256) void prep_all(const float* __restrict__ x,
                                                const float* __restrict__ W_enc,
                                                const float* __restrict__ W_dec,
                                                const float* __restrict__ b_dec,
                                                unsigned short* __restrict__ wencb,
                                                unsigned short* __restrict__ xbarb,
                                                float* __restrict__ srow,
                                                unsigned short* __restrict__ WdTb,
                                                int* __restrict__ cand_cnt) {
  __shared__ float tile[32][33];
  __shared__ float wsum[4];
  const int t = threadIdx.x;
  const int bid = blockIdx.x;
  if (bid < 16384) {                       // W_enc fp32 -> bf16
    size_t i = (size_t)bid * 256 + t;
    float4 v = ((const float4*)W_enc)[i];
    ushort4 o;
    o.x = f2bf(v.x); o.y = f2bf(v.y); o.z = f2bf(v.z); o.w = f2bf(v.w);
    ((ushort4*)wencb)[i] = o;
  } else if (bid < 20480) {                // xbar bf16 + per-row sigma + cnt zero
    const int b = bid - 16384;
    if (t == 0) cand_cnt[b * CNT_STRIDE] = 0;
    float4 v = ((const float4*)x)[(size_t)b * 256 + t];
    float4 bd = ((const float4*)b_dec)[t];
    float4 e = make_float4(v.x - bd.x, v.y - bd.y, v.z - bd.z, v.w - bd.w);
    ushort4 o;
    o.x = f2bf(e.x); o.y = f2bf(e.y); o.z = f2bf(e.z); o.w = f2bf(e.w);
    ((ushort4*)xbarb)[(size_t)b * 256 + t] = o;
    float ss = e.x * e.x + e.y * e.y + e.z * e.z + e.w * e.w;
#pragma unroll
    for (int off = 32; off; off >>= 1) ss += __shfl_down(ss, off);
    if ((t & 63) == 0) wsum[t >> 6] = ss;
    __syncthreads();
    if (t == 0) srow[b] = sqrtf((wsum[0] + wsum[1] + wsum[2] + wsum[3]) * (1.0f / D_N));
  } else {                                 // W_dec [D][L] -> W_decT bf16 [L][D]
    const int tb = bid - 20480;
    const int l0 = (tb & 511) * 32;        // L/32 = 512
    const int d0 = (tb >> 9) * 32;
    const int tx = t & 31, ty = t >> 5;
    for (int i = ty; i < 32; i += 8)
      tile[i][tx] = W_dec[(size_t)(d0 + i) * L_N + l0 + tx];
    __syncthreads();
    for (int i = ty; i < 32; i += 8)
      WdTb[(size_t)(l0 + i) * D_N + d0 + tx] = f2bf(tile[tx][i]);
  }
}

// ---------------- encoder GEMM 256x256, BK=64, 8 waves, dbuf 128KB LDS ----------------
// Deep-pipelined structure (T1 XCD swizzle + T2 st-swizzle + phase interleave + T5
// setprio). Tile k+1 staged via global_load_lds at top of iteration k (other
// buffer); one vmcnt(0)+barrier per K-tile, loads are 4 phases old at the drain.
// LDS layout: buf p at p*65536; A tile [256][64]bf16 at +0, B tile at +32768.
// Swizzle involution: in-row 16B unit u_phys = u_log ^ (row&7); applied on the
// global SOURCE address at staging (linear LDS dest) and on ds_read addresses.
// Epilogue: bias + 2.3*sigma candidate append + f-tile zero (unchanged semantics,
// same per-element accumulation order as previous kernel -> bitwise-identical C).
__global__ __launch_bounds__(512, 2) void gemm_enc_select(
    const unsigned short* __restrict__ A,   // xbar bf16 [B][D]
    const unsigned short* __restrict__ Bw,  // W_enc bf16 [L][D]
    const float* __restrict__ b_enc,
    const float* __restrict__ srow,
    int* __restrict__ cand_cnt,             // [B] stride CNT_STRIDE
    float* __restrict__ cand_val,           // [B][CAP]
    int* __restrict__ cand_idx,             // [B][CAP]
    float* __restrict__ f) {                // [B][L] zeroed here (tile-local)
  __shared__ __align__(16) char smem[131072];
  const int tid = threadIdx.x;
  const int wid = tid >> 6, lane = tid & 63;
  const int wm = wid >> 2, wn = wid & 3;    // 2 x 4 wave grid
  const int fr = lane & 15, quad = lane >> 4;

  // bijective XCD swizzle: 1024 blocks, 1024 % 8 == 0
  const int wg = ((blockIdx.x & 7) << 7) + (blockIdx.x >> 3);
  const int bm = wg & 15, bn = wg >> 4;     // 16 x 64 tiles

  // staging geometry: instr r covers LDS rows r*64 + wid*8 + (lane>>3);
  // lane&7 selects the 16B unit in the 128B row; source col pre-swizzled.
  const int stgrow = wid * 8 + (lane >> 3);
  const int scol = ((lane & 7) ^ (lane >> 3)) << 4;
  const char* gA = (const char*)A + ((size_t)(bm * 256 + stgrow) * D_N) * 2 + scol;
  const char* gB = (const char*)Bw + ((size_t)(bn * 256 + stgrow) * D_N) * 2 + scol;

#define STAGE(kt_, p_)                                                                   \
  {                                                                                      \
    const size_t ko_ = (size_t)(kt_)*128;                                                \
    _Pragma("unroll") for (int r_ = 0; r_ < 4; ++r_) {                                   \
      __builtin_amdgcn_global_load_lds(                                                  \
          (const __attribute__((address_space(1))) void*)(gA + (size_t)r_ * 131072 + ko_), \
          (__attribute__((address_space(3))) void*)(smem + (p_)*65536 + r_ * 8192 + wid * 1024), \
          16, 0, 0);                                                                     \
      __builtin_amdgcn_global_load_lds(                                                  \
          (const __attribute__((address_space(1))) void*)(gB + (size_t)r_ * 131072 + ko_), \
          (__attribute__((address_space(3))) void*)(smem + (p_)*65536 + 32768 + r_ * 8192 + wid * 1024), \
          16, 0, 0);                                                                     \
    }                                                                                    \
  }

  f32x4 acc[8][4];
#pragma unroll
  for (int i = 0; i < 8; ++i)
#pragma unroll
    for (int j = 0; j < 4; ++j) acc[i][j] = (f32x4){0.f, 0.f, 0.f, 0.f};

  // per-lane ds_read bases (byte offsets); row stride 128B
  const int aB = (wm * 128 + fr) * 128;
  const int bB = 32768 + (wn * 64 + fr) * 128;
  const int s0 = (quad ^ (fr & 7)) << 4;   // swizzled unit for ks=0; ks=1 is ^64

  STAGE(0, 0);
  __syncthreads();   // drain tile-0 loads (vmcnt 0 + barrier)

// one phase: quadrant (mh_, ks_) -> 8 ds_read_b128 + 16 MFMA
#define PHASE(mh_, ks_, TRAIL_)                                                          \
  {                                                                                      \
    bf16x8 af[4], bv[4];                                                                 \
    _Pragma("unroll") for (int i_ = 0; i_ < 4; ++i_)                                     \
        af[i_] = *(const bf16x8*)(smem + pb + aB + ((mh_)*64 + i_ * 16) * 128 +          \
                                  (s0 ^ ((ks_)*64)));                                    \
    _Pragma("unroll") for (int j_ = 0; j_ < 4; ++j_)                                     \
        bv[j_] = *(const bf16x8*)(smem + pb + bB + j_ * 2048 + (s0 ^ ((ks_)*64)));       \
    __builtin_amdgcn_s_barrier();                                                        \
    asm volatile("s_waitcnt lgkmcnt(0)" ::: "memory");                                   \
    __builtin_amdgcn_sched_barrier(0);                                                   \
    __builtin_amdgcn_s_setprio(1);                                                       \
    _Pragma("unroll") for (int i_ = 0; i_ < 4; ++i_)                                     \
        _Pragma("unroll") for (int j_ = 0; j_ < 4; ++j_)                                 \
            acc[(mh_)*4 + i_][j_] = __builtin_amdgcn_mfma_f32_16x16x32_bf16(             \
                af[i_], bv[j_], acc[(mh_)*4 + i_][j_], 0, 0, 0);                         \
    __builtin_amdgcn_s_setprio(0);                                                       \
    if (TRAIL_) __builtin_amdgcn_s_barrier();                                            \
  }

  for (int kt = 0; kt < D_N / 64; ++kt) {
    const int pb = (kt & 1) * 65536;
    if (kt < D_N / 64 - 1) STAGE(kt + 1, (kt & 1) ^ 1);
    PHASE(0, 0, 1)
    PHASE(1, 0, 1)
    PHASE(0, 1, 1)
    PHASE(1, 1, 0)
    if (kt < D_N / 64 - 1) {
      asm volatile("s_waitcnt vmcnt(0)" ::: "memory");   // tile kt+1 landed
      __builtin_amdgcn_s_barrier();                      // all waves' reads of buf done
    }
  }

  // epilogue: D layout col=lane&15, row=quad*4+reg  [m89-verified]
  const int lc0 = bn * 256 + wn * 64 + fr;
  float be[4];
#pragma unroll
  for (int nj = 0; nj < 4; ++nj) be[nj] = b_enc[lc0 + nj * 16];
  const int gr0 = bm * 256 + wm * 128 + quad * 4;
#pragma unroll
  for (int mi = 0; mi < 8; ++mi) {
#pragma unroll
    for (int r = 0; r < 4; ++r) {
      const int grow = gr0 + mi * 16 + r;
      const float thr = 2.3f * srow[grow];
#pragma unroll
      for (int nj = 0; nj < 4; ++nj) {
        const float val = acc[mi][nj][r] + be[nj];
        if (val > thr) {
          const int p = atomicAdd(&cand_cnt[grow * CNT_STRIDE], 1);
          if (p < CAP) {
            cand_val[(size_t)grow * CAP + p] = val;
            cand_idx[(size_t)grow * CAP + p] = lc0 + nj * 16;
          }
        }
      }
    }
  }

  // zero this block's 256x256 f tile LAST — fire-and-forget streaming stores
  {
    const float4 z4 = make_float4(0.f, 0.f, 0.f, 0.f);
    float4* fz = (float4*)(f + (size_t)(bm * 256) * L_N + bn * 256);
#pragma unroll
    for (int it = 0; it < 32; ++it) {
      const int idx = it * 512 + tid;          // 0..16383 float4 slots
      const int rr = idx >> 6, cc = idx & 63;  // 64 float4 per tile row
      fz[(size_t)rr * (L_N / 4) + cc] = z4;
    }
  }
#undef STAGE
#undef PHASE
}

// ---------------- select + fp64 refine + scatter f + fused decode ----------------
__global__ __launch_bounds__(256) void select_decode(
    const float* __restrict__ x,
    const float* __restrict__ W_enc,
    const float* __restrict__ b_enc,
    const float* __restrict__ b_dec,
    const float* __restrict__ srow,
    const int* __restrict__ cand_cnt,
    const float* __restrict__ cand_val,
    const int* __restrict__ cand_idx,
    const unsigned short* __restrict__ WdTb,
    float* __restrict__ f,
    float* __restrict__ xhat) {
  const int b = blockIdx.x, t = threadIdx.x;
  const int lane = t & 63, wave = t >> 6;
  __shared__ double xd[D_N];       // exact xbar in fp64
  __shared__ float cv[CAP];
  __shared__ int ci[CAP];
  __shared__ double bu[128];       // boundary fp64 scores
  __shared__ int bidx[128];        // boundary slot -> cand slot
  __shared__ int o_idx[K_N];
  __shared__ float o_val[K_N];
  __shared__ int sidx[K_N];
  __shared__ float sval[K_N];
  __shared__ int nb_s, nin_s, outcnt;
  __shared__ float v64_s;

  const int cnt = min(cand_cnt[b * CNT_STRIDE], CAP);
  if (t == 0) { nb_s = 0; nin_s = 0; outcnt = 0; v64_s = -1e30f; }
  for (int c = t; c < cnt; c += 256) {
    cv[c] = cand_val[(size_t)b * CAP + c];
    ci[c] = cand_idx[(size_t)b * CAP + c];
  }
  for (int i = t; i < D_N; i += 256)
    xd[i] = (double)x[(size_t)b * D_N + i] - (double)b_dec[i];
  __syncthreads();

  // v64 = 64th-largest approx value (unique by (val, idx) lexicographic)
  for (int c = t; c < cnt; c += 256) {
    const float v = cv[c];
    const int id = ci[c];
    int r = 0;
    for (int k = 0; k < cnt; ++k)
      r += (cv[k] > v || (cv[k] == v && ci[k] < id)) ? 1 : 0;
    if (r == 63) v64_s = v;   // unique writer
  }
  __syncthreads();
  const float v64 = v64_s;
  const float m = 0.04f * srow[b];

  // classify: definite-in (v > v64+m), boundary (|v - v64| <= m)
  for (int c = t; c < cnt; c += 256) {
    const float v = cv[c];
    if (v > v64 + m) {
      atomicAdd(&nin_s, 1);
    } else if (v >= v64 - m) {
      const int p = atomicAdd(&nb_s, 1);
      if (p < 128) bidx[p] = c;
    }
  }
  __syncthreads();
  const int nb = min(nb_s, 128);
  const int nin = nin_s;
  int nneed = K_N - nin;
  if (nneed < 0) nneed = 0;

  // fp64 exact scores for boundary candidates (one wave per candidate)
  for (int c = wave; c < nb; c += 4) {
    const int l = ci[bidx[c]];
    const float4* wr = (const float4*)(W_enc + (size_t)l * D_N);
    double acc = 0.0;
#pragma unroll
    for (int j = 0; j < 4; ++j) {
      float4 w4 = wr[j * 64 + lane];
      const int base = (j * 64 + lane) * 4;
      acc += xd[base + 0] * (double)w4.x + xd[base + 1] * (double)w4.y +
             xd[base + 2] * (double)w4.z + xd[base + 3] * (double)w4.w;
    }
#pragma unroll
    for (int off = 32; off; off >>= 1) acc += __shfl_down(acc, off);
    if (lane == 0) bu[c] = acc + (double)b_enc[l];
  }
  __syncthreads();

  // emit definite-ins with approx values
  for (int c = t; c < cnt; c += 256) {
    if (cv[c] > v64 + m) {
      const int p = atomicAdd(&outcnt, 1);
      if (p < K_N) { o_idx[p] = ci[c]; o_val[p] = cv[c]; }
    }
  }
  // emit best nneed boundary candidates by exact fp64 score
  if (t < nb) {
    const double uv = bu[t];
    const int l = ci[bidx[t]];
    int r = 0;
    for (int k = 0; k < nb; ++k)
      r += (bu[k] > uv || (bu[k] == uv && ci[bidx[k]] < l)) ? 1 : 0;
    if (r < nneed) {
      const int p = atomicAdd(&outcnt, 1);
      if (p < K_N) { o_idx[p] = l; o_val[p] = (float)uv; }
    }
  }
  __syncthreads();
  const int ns = min(outcnt, K_N);

  if (t < K_N) {
    sidx[t] = (t < ns) ? o_idx[t] : t;
    sval[t] = (t < ns) ? fmaxf(o_val[t], 0.0f) : 0.0f;
  }
  __syncthreads();

  // scatter into f (tile already zeroed by gemm)
  if (t < ns) f[(size_t)b * L_N + sidx[t]] = sval[t];

  // fused decode: xhat row = sum_k sval[k] * W_decT[sidx[k],:] + b_dec
  float4 acc = ((const float4*)b_dec)[t];   // 256 float4 == D_N
#pragma unroll 8
  for (int k = 0; k < K_N; ++k) {
    const float v = sval[k];
    const ushort4 w = ((const ushort4*)(WdTb + (size_t)sidx[k] * D_N))[t];
    acc.x += v * bf2f(w.x); acc.y += v * bf2f(w.y);
    acc.z += v * bf2f(w.z); acc.w += v * bf2f(w.w);
  }
  ((float4*)(xhat + (size_t)b * D_N))[t] = acc;
}

extern "C" void kernel_launch(void* const* d_in, const int* in_sizes, int n_in,
                              void* d_out, int out_size, void* d_ws, size_t ws_size,
                              hipStream_t stream) {
  (void)in_sizes; (void)n_in; (void)out_size; (void)ws_size;
  const float* x     = (const float*)d_in[0];   // [B][D]
  const float* W_enc = (const float*)d_in[1];   // [L][D]
  const float* b_enc = (const float*)d_in[2];   // [L]
  const float* W_dec = (const float*)d_in[3];   // [D][L]
  const float* b_dec = (const float*)d_in[4];   // [D]

  float* f    = (float*)d_out;                        // [B][L]
  float* xhat = (float*)d_out + (size_t)B_N * L_N;    // [B][D]

  // workspace layout (~92 MB total)
  char* ws = (char*)d_ws;
  unsigned short* wencb = (unsigned short*)ws;                   // 32 MB bf16 W_enc
  unsigned short* xbarb = (unsigned short*)(ws + 33554432);      //  8 MB bf16 xbar
  unsigned short* WdTb  = (unsigned short*)(ws + 41943040);      // 32 MB bf16 W_dec^T
  float* srow           = (float*)(ws + 75497472);               // 16 KB
  int* cand_cnt         = (int*)(ws + 75513856);                 // 256 KB (line-padded)
  float* cand_val       = (float*)(ws + 75776000);               //  8 MB
  int* cand_idx         = (int*)(ws + 84164608);                 //  8 MB

  prep_all<<<36864, 256, 0, stream>>>(x, W_enc, W_dec, b_dec, wencb, xbarb, srow,
                                      WdTb, cand_cnt);
  gemm_enc_select<<<1024, 512, 0, stream>>>(
      xbarb, wencb, b_enc, srow, cand_cnt, cand_val, cand_idx, f);
  select_decode<<<B_N, 256, 0, stream>>>(x, W_enc, b_enc, b_dec, srow,
                                         cand_cnt, cand_val, cand_idx, WdTb, f, xhat);
}